// Round 16
// baseline (270.562 us; speedup 1.0000x reference)
//
#include <hip/hip_runtime.h>

// LightGCN: final = (x0 + x1 + x2 + x3) / 4, x_{l+1}[r] = sum_{e:row=r} x_l[col_e]*norm_e
// norm_e = rsqrt(deg[row_e]) * rsqrt(deg[col_e]), deg = clip(bincount(row),1)
// N = 150000 nodes, d = 64, E = 2.4M edges. Output fp32.
//
// R28 = R27 (verified 267.8us) + PART_BLOCKS 256->512.
// Theory: partition is latency/barrier-bound at 1 block/CU (1024 thr,
// 51KB LDS, ~25 serial barrier phases). Halving per-block edges (9376->
// 4688) halves staged LDS (37.5->18.8KB, total ~32KB) -> 2 blocks/CU
// co-resident hide each other's barriers + per-block work halves.
// Standing lessons: identity node order (R21/R25); int LDS atomics only
// (R23); x-tables 4096-B aligned (R15); LDS-staged global writes
// (R22 partition, R27 fine); no reservation stagger (R26: neutral).

#define NUM_USERS 100000
#define NUM_ITEMS 50000
#define EMBED_DIM 64
#define N_NODES   150000
#define N_EDGES   2400000
#define N_BUCKETS 586       // ceil(150000/256), 256 rows per bucket
#define BCAP      4608      // static per-bucket window (ints)
#define PART_BLOCKS 512
#define MAX_BLK_EDGES 4688  // ceil(600000/512)*4

// ws layout (byte offsets), total 51,013,760 <= proven 51,033,344:
#define OFF_BCNT  0         // int32 x 586 (zeroed per launch)
#define OFF_BE    8192      // int2 x N {beg,end}            (ends 1,208,192; 128-aligned)
#define OFF_PS    1808256   // int32 x 586*4608 (128-aligned; ends 12,609,408)
#define OFF_XA    12611584  // bf16 x (N+1)*64 = 19,200,128  (4096-aligned; ends 31,811,712)
#define OFF_XB    31813632  // bf16 x (N+1)*64               (4096-aligned; ends 51,013,760)

__device__ __forceinline__ unsigned f2bf(float f) {  // RNE fp32 -> bf16 (as u16)
    unsigned u = __float_as_uint(f);
    return (u + 0x7fffu + ((u >> 16) & 1u)) >> 16;
}
__device__ __forceinline__ float bflo(unsigned u) { return __uint_as_float(u << 16); }
__device__ __forceinline__ float bfhi(unsigned u) { return __uint_as_float(u & 0xffff0000u); }
__device__ __forceinline__ float2 bf2(unsigned u) {  // bf16 pair -> float2
    float2 r; r.x = bflo(u); r.y = bfhi(u); return r;
}

// Pass 1: partition into static bucket windows, LDS-staged for coalesced
// writes. pack = (row&255)<<18 | col. Block 0 zeroes the dummy rows.
__global__ void partition_kernel(const int4* __restrict__ row4, const int4* __restrict__ col4,
                                 int* __restrict__ bcnt, unsigned* __restrict__ ps,
                                 uint2* __restrict__ yA, uint2* __restrict__ yB) {
    __shared__ int scanws[1024];                 // scan workspace (padded hist)
    __shared__ int lsize[N_BUCKETS];             // per-bucket count in this block
    __shared__ int lstart[N_BUCKETS + 1];        // exclusive starts in staged[]
    __shared__ int gbase[N_BUCKETS];             // reserved global bases
    __shared__ int lcur[N_BUCKETS];              // scatter cursors
    __shared__ unsigned staged[MAX_BLK_EDGES];   // bucket-sorted packed edges
    if (blockIdx.x == 0 && threadIdx.x < 16) {   // dummy row N_NODES of both tables
        uint2 z; z.x = 0u; z.y = 0u;
        yA[2400000 + threadIdx.x] = z;
        yB[2400000 + threadIdx.x] = z;
    }
    scanws[threadIdx.x] = 0;
    __syncthreads();
    const int total4 = N_EDGES / 4;
    int per4 = (total4 + gridDim.x - 1) / gridDim.x;
    int s4 = blockIdx.x * per4;
    int e4 = s4 + per4; if (e4 > total4) e4 = total4;
    const int cntE = (e4 - s4) * 4;
    // 1) histogram
    for (int i = s4 + (int)threadIdx.x; i < e4; i += (int)blockDim.x) {
        int4 r = row4[i];
        atomicAdd(&scanws[r.x >> 8], 1);
        atomicAdd(&scanws[r.y >> 8], 1);
        atomicAdd(&scanws[r.z >> 8], 1);
        atomicAdd(&scanws[r.w >> 8], 1);
    }
    __syncthreads();
    int myv = scanws[threadIdx.x];               // padded: 0 for t >= N_BUCKETS
    if (threadIdx.x < N_BUCKETS) lsize[threadIdx.x] = myv;
    __syncthreads();
    // 2) Hillis-Steele inclusive scan over 1024 (covers 586)
    for (int off = 1; off < 1024; off <<= 1) {
        int t = (threadIdx.x >= off) ? scanws[threadIdx.x - off] : 0;
        __syncthreads();
        scanws[threadIdx.x] += t;
        __syncthreads();
    }
    if (threadIdx.x < N_BUCKETS) {
        int incl = scanws[threadIdx.x];
        int st = incl - lsize[threadIdx.x];
        lstart[threadIdx.x] = st;
        lcur[threadIdx.x] = st;
        int c = lsize[threadIdx.x];
        gbase[threadIdx.x] = c ? (threadIdx.x * BCAP + atomicAdd(&bcnt[threadIdx.x], c)) : 0;
    }
    if (threadIdx.x == 0) lstart[N_BUCKETS] = cntE;
    __syncthreads();
    // 3) scatter into bucket-sorted LDS
    for (int i = s4 + (int)threadIdx.x; i < e4; i += (int)blockDim.x) {
        int4 r = row4[i];
        int4 c = col4[i];
        int pos;
        pos = atomicAdd(&lcur[r.x >> 8], 1); staged[pos] = ((unsigned)(r.x & 255) << 18) | (unsigned)c.x;
        pos = atomicAdd(&lcur[r.y >> 8], 1); staged[pos] = ((unsigned)(r.y & 255) << 18) | (unsigned)c.y;
        pos = atomicAdd(&lcur[r.z >> 8], 1); staged[pos] = ((unsigned)(r.z & 255) << 18) | (unsigned)c.z;
        pos = atomicAdd(&lcur[r.w >> 8], 1); staged[pos] = ((unsigned)(r.w & 255) << 18) | (unsigned)c.w;
    }
    __syncthreads();
    // 4) sequential writeback: consecutive i -> consecutive dest within runs
    for (int i = (int)threadIdx.x; i < cntE; i += (int)blockDim.x) {
        int lo = 0, hi = N_BUCKETS - 1;          // largest b with lstart[b] <= i
        while (lo < hi) {
            int mid = (lo + hi + 1) >> 1;
            if (lstart[mid] <= i) lo = mid; else hi = mid - 1;
        }
        ps[gbase[lo] + (i - lstart[lo])] = staged[i];
    }
}

// Pass 2: one block (512 thr) per bucket. Stage bucket edges in LDS, build
// 256-row hist, even-padded row starts, be, row-sort into LDS lsort,
// SEQUENTIAL coalesced ps writeback, and y0 = x0*rsqrt(deg) rows.
__global__ void fine_kernel(const int* __restrict__ bcnt, int* __restrict__ ps,
                            int2* __restrict__ be,
                            const float4* __restrict__ user, const float4* __restrict__ item,
                            uint2* __restrict__ yA) {
    __shared__ int ledge[BCAP];
    __shared__ int lsort[BCAP];
    __shared__ int rh[256];
    __shared__ int rsc[256];
    __shared__ int rcur[256];
    __shared__ float rq[256];
    int b = blockIdx.x;
    int base = b * BCAP;
    int cnt  = bcnt[b];
    if (cnt > BCAP) cnt = BCAP;          // defensive (never expected)
    if (threadIdx.x < 256) rh[threadIdx.x] = 0;
    __syncthreads();
    for (int i = threadIdx.x; i < cnt; i += blockDim.x) {
        int p = ps[base + i];
        ledge[i] = p;
        atomicAdd(&rh[p >> 18], 1);
    }
    __syncthreads();
    if (threadIdx.x < 256) rsc[threadIdx.x] = (rh[threadIdx.x] + 1) & ~1;  // even row size
    __syncthreads();
    for (int off = 1; off < 256; off <<= 1) {
        int t = (threadIdx.x < 256 && threadIdx.x >= off) ? rsc[threadIdx.x - off] : 0;
        __syncthreads();
        if (threadIdx.x < 256) rsc[threadIdx.x] += t;
        __syncthreads();
    }
    if (threadIdx.x < 256) {
        int r = threadIdx.x;
        int sz = (rh[r] + 1) & ~1;
        int pstart = rsc[r] - sz;            // even (base even, sizes even)
        rcur[r] = pstart;
        int n = (b << 8) + r;
        if (n < N_NODES) {
            int2 p; p.x = base + pstart; p.y = base + pstart + rh[r];
            be[n] = p;
            float d = (float)(rh[r] < 1 ? 1 : rh[r]);
            rq[r] = rsqrtf(d);
        }
    }
    __syncthreads();
    // row-sort scatter into LDS (int LDS atomics + LDS writes only)
    for (int i = threadIdx.x; i < cnt; i += blockDim.x) {
        int p = ledge[i];
        int pos = atomicAdd(&rcur[p >> 18], 1);      // LDS atomic
        lsort[pos] = p & 0x3FFFF;                    // sorted col, row bits stripped
    }
    __syncthreads();
    // sequential coalesced writeback of the padded layout (pads = garbage,
    // discarded by pull predicates before address formation)
    int tot = rsc[255];                              // padded total
    if (tot > BCAP) tot = BCAP;                      // defensive
    for (int i = threadIdx.x; i < tot; i += blockDim.x)
        ps[base + i] = lsort[i];
    // y0 rows for this bucket: 256 rows x 16 uint2 words; word w covers float4 w.
    for (int idx = threadIdx.x; idx < 4096; idx += blockDim.x) {
        int r = idx >> 4, w = idx & 15;
        int n = (b << 8) + r;
        if (n < N_NODES) {
            const float4* src = (n < NUM_USERS) ? (user + (size_t)n * 16)
                                                : (item + (size_t)(n - NUM_USERS) * 16);
            float4 v = src[w];
            float rn = rq[r];
            uint2 o;
            o.x = f2bf(v.x * rn) | (f2bf(v.y * rn) << 16);
            o.y = f2bf(v.z * rn) | (f2bf(v.w * rn) << 16);
            yA[(size_t)n * 16 + w] = o;
        }
    }
}

// 8 lanes per node, 8 nodes per wave (identity order: consecutive nodes ->
// contiguous scol runs + contiguous stores; R21/R25 lesson: ANY reorder
// loses). Lane q owns dims [8q,8q+8); 8-edge unroll: 4 int2 scol + 8 uint4
// gathers in flight. OOB -> dummy zero row N_NODES, predicated BEFORE
// addressing. Over-read <=24B past ps end lands in the slack before XA.
__device__ __forceinline__ void pull_sum(int2 bnd, int q,
                                         const int2* __restrict__ scol2,
                                         const uint4* __restrict__ xin, float2 sum[4]) {
    int endj = bnd.y;
    for (int j = bnd.x; j < endj; j += 8) {
        int h = j >> 1;
        int2 cc0 = scol2[h];
        int2 cc1 = scol2[h + 1];
        int2 cc2 = scol2[h + 2];
        int2 cc3 = scol2[h + 3];
        int c0 = cc0.x;                               // j < endj by loop cond
        int c1 = (j + 1 < endj) ? cc0.y : N_NODES;
        int c2 = (j + 2 < endj) ? cc1.x : N_NODES;
        int c3 = (j + 3 < endj) ? cc1.y : N_NODES;
        int c4 = (j + 4 < endj) ? cc2.x : N_NODES;
        int c5 = (j + 5 < endj) ? cc2.y : N_NODES;
        int c6 = (j + 6 < endj) ? cc3.x : N_NODES;
        int c7 = (j + 7 < endj) ? cc3.y : N_NODES;
        uint4 X0 = xin[(size_t)c0 * 8 + q];
        uint4 X1 = xin[(size_t)c1 * 8 + q];
        uint4 X2 = xin[(size_t)c2 * 8 + q];
        uint4 X3 = xin[(size_t)c3 * 8 + q];
        uint4 X4 = xin[(size_t)c4 * 8 + q];
        uint4 X5 = xin[(size_t)c5 * 8 + q];
        uint4 X6 = xin[(size_t)c6 * 8 + q];
        uint4 X7 = xin[(size_t)c7 * 8 + q];
        sum[0] += (bf2(X0.x) + bf2(X1.x)) + (bf2(X2.x) + bf2(X3.x))
                + (bf2(X4.x) + bf2(X5.x)) + (bf2(X6.x) + bf2(X7.x));
        sum[1] += (bf2(X0.y) + bf2(X1.y)) + (bf2(X2.y) + bf2(X3.y))
                + (bf2(X4.y) + bf2(X5.y)) + (bf2(X6.y) + bf2(X7.y));
        sum[2] += (bf2(X0.z) + bf2(X1.z)) + (bf2(X2.z) + bf2(X3.z))
                + (bf2(X4.z) + bf2(X5.z)) + (bf2(X6.z) + bf2(X7.z));
        sum[3] += (bf2(X0.w) + bf2(X1.w)) + (bf2(X2.w) + bf2(X3.w))
                + (bf2(X4.w) + bf2(X5.w)) + (bf2(X6.w) + bf2(X7.w));
    }
}

// Middle layers: y_{l+1}[n] = rsqrt(deg)^2 * sum  (bf16). All 64 lanes store.
__global__ void pull_kernel(const int2* __restrict__ be,
                            const int2* __restrict__ scol2,
                            const uint4* __restrict__ xin, uint4* __restrict__ xout) {
    int t = blockIdx.x * blockDim.x + (int)threadIdx.x;
    int n = t >> 3;
    if (n >= N_NODES) return;
    int q = t & 7;
    int2 bnd = be[n];
    float2 sum[4];
    sum[0] = make_float2(0.f, 0.f); sum[1] = make_float2(0.f, 0.f);
    sum[2] = make_float2(0.f, 0.f); sum[3] = make_float2(0.f, 0.f);
    pull_sum(bnd, q, scol2, xin, sum);
    int deg = bnd.y - bnd.x;
    float d = (float)(deg < 1 ? 1 : deg);
    float rn = rsqrtf(d);
    float s2 = rn * rn;
    uint4 p;
    p.x = f2bf(sum[0].x * s2) | (f2bf(sum[0].y * s2) << 16);
    p.y = f2bf(sum[1].x * s2) | (f2bf(sum[1].y * s2) << 16);
    p.z = f2bf(sum[2].x * s2) | (f2bf(sum[2].y * s2) << 16);
    p.w = f2bf(sum[3].x * s2) | (f2bf(sum[3].y * s2) << 16);
    xout[(size_t)n * 8 + q] = p;
}

// Last layer: acc = (x0 + (y1+y2)*sd + rn*sum) / 4, rn = rsqrt(deg), sd = sqrt(deg).
__global__ void pull_last_kernel(const int2* __restrict__ be,
                                 const int2* __restrict__ scol2,
                                 const uint4* __restrict__ xin,   // y2 (gather table)
                                 const uint4* __restrict__ xprev, // y1
                                 const float4* __restrict__ user, const float4* __restrict__ item,
                                 float4* __restrict__ acc4) {
    int t = blockIdx.x * blockDim.x + (int)threadIdx.x;
    int n = t >> 3;
    if (n >= N_NODES) return;
    int q = t & 7;
    int2 bnd = be[n];
    float2 sum[4];
    sum[0] = make_float2(0.f, 0.f); sum[1] = make_float2(0.f, 0.f);
    sum[2] = make_float2(0.f, 0.f); sum[3] = make_float2(0.f, 0.f);
    pull_sum(bnd, q, scol2, xin, sum);
    int deg = bnd.y - bnd.x;
    float d = (float)(deg < 1 ? 1 : deg);
    float rn = rsqrtf(d);
    float sd = sqrtf(d);
    uint4 p2 = xin  [(size_t)n * 8 + q];
    uint4 p1 = xprev[(size_t)n * 8 + q];
    const float4* x0 = (n < NUM_USERS) ? (user + (size_t)n * 16)
                                       : (item + (size_t)(n - NUM_USERS) * 16);
    float4 a0 = x0[q * 2], a1 = x0[q * 2 + 1];
    float4 o0, o1;
    o0.x = (a0.x + (bflo(p1.x) + bflo(p2.x)) * sd + rn * sum[0].x) * 0.25f;
    o0.y = (a0.y + (bfhi(p1.x) + bfhi(p2.x)) * sd + rn * sum[0].y) * 0.25f;
    o0.z = (a0.z + (bflo(p1.y) + bflo(p2.y)) * sd + rn * sum[1].x) * 0.25f;
    o0.w = (a0.w + (bfhi(p1.y) + bfhi(p2.y)) * sd + rn * sum[1].y) * 0.25f;
    o1.x = (a1.x + (bflo(p1.z) + bflo(p2.z)) * sd + rn * sum[2].x) * 0.25f;
    o1.y = (a1.y + (bfhi(p1.z) + bfhi(p2.z)) * sd + rn * sum[2].y) * 0.25f;
    o1.z = (a1.z + (bflo(p1.w) + bflo(p2.w)) * sd + rn * sum[3].x) * 0.25f;
    o1.w = (a1.w + (bfhi(p1.w) + bfhi(p2.w)) * sd + rn * sum[3].y) * 0.25f;
    size_t o4 = (size_t)n * 16 + q * 2;
    acc4[o4] = o0;
    acc4[o4 + 1] = o1;
}

extern "C" void kernel_launch(void* const* d_in, const int* in_sizes, int n_in,
                              void* d_out, int out_size, void* d_ws, size_t ws_size,
                              hipStream_t stream) {
    const float* user = (const float*)d_in[0];
    const float* item = (const float*)d_in[1];
    const int*   ei   = (const int*)d_in[2];
    const int* row = ei;            // edge_index[0]
    const int* col = ei + N_EDGES;  // edge_index[1]

    char*  ws   = (char*)d_ws;
    int*   bcnt = (int*)(ws + OFF_BCNT);
    int2*  be   = (int2*)(ws + OFF_BE);
    int*   ps   = (int*)(ws + OFF_PS);
    char*  xA   = ws + OFF_XA;   // bf16 y-tables, (N+1) rows (row N = zeros)
    char*  xB   = ws + OFF_XB;
    float* acc  = (float*)d_out;

    // CSR build: LDS-staged partition (2 blocks/CU) -> fine (LDS sort)
    hipMemsetAsync(bcnt, 0, 4096, stream);
    partition_kernel<<<PART_BLOCKS, 1024, 0, stream>>>((const int4*)row, (const int4*)col,
                                                       bcnt, (unsigned*)ps,
                                                       (uint2*)xA, (uint2*)xB);
    fine_kernel<<<N_BUCKETS, 512, 0, stream>>>(bcnt, ps, be,
                                               (const float4*)user, (const float4*)item,
                                               (uint2*)xA);

    // 3 pull layers: 8 threads per node, identity node order
    const int grid = (N_NODES * 8 + 255) / 256;
    pull_kernel<<<grid, 256, 0, stream>>>(be, (const int2*)ps,
        (const uint4*)xA, (uint4*)xB);
    pull_kernel<<<grid, 256, 0, stream>>>(be, (const int2*)ps,
        (const uint4*)xB, (uint4*)xA);
    pull_last_kernel<<<grid, 256, 0, stream>>>(be, (const int2*)ps,
        (const uint4*)xA, (const uint4*)xB,
        (const float4*)user, (const float4*)item, (float4*)acc);
}

// Round 18
// 268.344 us; speedup vs baseline: 1.0083x; 1.0083x over previous
//
#include <hip/hip_runtime.h>

// LightGCN: final = (x0 + x1 + x2 + x3) / 4, x_{l+1}[r] = sum_{e:row=r} x_l[col_e]*norm_e
// norm_e = rsqrt(deg[row_e]) * rsqrt(deg[col_e]), deg = clip(bincount(row),1)
// N = 150000 nodes, d = 64, E = 2.4M edges. Output fp32.
//
// R30 = R29 resubmit (GPU broker timeout, no bench ran; kernel unchanged):
// bktid[] LDS array kills partition's writeback binary search (10 dependent
// ds_reads ~120cy each = ~1200cy chain per element, ~9 chains/thread).
// Bucket is KNOWN at scatter time (row>>8): record in 16-bit bktid[pos],
// writeback = independent LDS reads. LDS ~41.5KB.
// Standing lessons: identity node order (R21/R25); int LDS atomics only
// (R23); x-tables 4096-B aligned (R15); LDS-staged global writes (R22/R27).

#define NUM_USERS 100000
#define NUM_ITEMS 50000
#define EMBED_DIM 64
#define N_NODES   150000
#define N_EDGES   2400000
#define N_BUCKETS 586       // ceil(150000/256), 256 rows per bucket
#define BCAP      4608      // static per-bucket window (ints)
#define PART_BLOCKS 512
#define MAX_BLK_EDGES 4688  // ceil(600000/512)*4

// ws layout (byte offsets), total 51,013,760 <= proven 51,033,344:
#define OFF_BCNT  0         // int32 x 586 (zeroed per launch)
#define OFF_BE    8192      // int2 x N {beg,end}            (ends 1,208,192; 128-aligned)
#define OFF_PS    1808256   // int32 x 586*4608 (128-aligned; ends 12,609,408)
#define OFF_XA    12611584  // bf16 x (N+1)*64 = 19,200,128  (4096-aligned; ends 31,811,712)
#define OFF_XB    31813632  // bf16 x (N+1)*64               (4096-aligned; ends 51,013,760)

__device__ __forceinline__ unsigned f2bf(float f) {  // RNE fp32 -> bf16 (as u16)
    unsigned u = __float_as_uint(f);
    return (u + 0x7fffu + ((u >> 16) & 1u)) >> 16;
}
__device__ __forceinline__ float bflo(unsigned u) { return __uint_as_float(u << 16); }
__device__ __forceinline__ float bfhi(unsigned u) { return __uint_as_float(u & 0xffff0000u); }
__device__ __forceinline__ float2 bf2(unsigned u) {  // bf16 pair -> float2
    float2 r; r.x = bflo(u); r.y = bfhi(u); return r;
}

// Pass 1: partition into static bucket windows, LDS-staged for coalesced
// writes. pack = (row&255)<<18 | col. Block 0 zeroes the dummy rows.
__global__ void partition_kernel(const int4* __restrict__ row4, const int4* __restrict__ col4,
                                 int* __restrict__ bcnt, unsigned* __restrict__ ps,
                                 uint2* __restrict__ yA, uint2* __restrict__ yB) {
    __shared__ int scanws[1024];                 // scan workspace (padded hist)
    __shared__ int lsize[N_BUCKETS];             // per-bucket count in this block
    __shared__ int lstart[N_BUCKETS + 1];        // exclusive starts in staged[]
    __shared__ int gbase[N_BUCKETS];             // reserved global bases
    __shared__ int lcur[N_BUCKETS];              // scatter cursors
    __shared__ unsigned staged[MAX_BLK_EDGES];   // bucket-sorted packed edges
    __shared__ unsigned short bktid[MAX_BLK_EDGES];  // bucket id per staged slot
    if (blockIdx.x == 0 && threadIdx.x < 16) {   // dummy row N_NODES of both tables
        uint2 z; z.x = 0u; z.y = 0u;
        yA[2400000 + threadIdx.x] = z;
        yB[2400000 + threadIdx.x] = z;
    }
    scanws[threadIdx.x] = 0;
    __syncthreads();
    const int total4 = N_EDGES / 4;
    int per4 = (total4 + gridDim.x - 1) / gridDim.x;
    int s4 = blockIdx.x * per4;
    int e4 = s4 + per4; if (e4 > total4) e4 = total4;
    const int cntE = (e4 - s4) * 4;
    // 1) histogram
    for (int i = s4 + (int)threadIdx.x; i < e4; i += (int)blockDim.x) {
        int4 r = row4[i];
        atomicAdd(&scanws[r.x >> 8], 1);
        atomicAdd(&scanws[r.y >> 8], 1);
        atomicAdd(&scanws[r.z >> 8], 1);
        atomicAdd(&scanws[r.w >> 8], 1);
    }
    __syncthreads();
    int myv = scanws[threadIdx.x];               // padded: 0 for t >= N_BUCKETS
    if (threadIdx.x < N_BUCKETS) lsize[threadIdx.x] = myv;
    __syncthreads();
    // 2) Hillis-Steele inclusive scan over 1024 (covers 586)
    for (int off = 1; off < 1024; off <<= 1) {
        int t = (threadIdx.x >= off) ? scanws[threadIdx.x - off] : 0;
        __syncthreads();
        scanws[threadIdx.x] += t;
        __syncthreads();
    }
    if (threadIdx.x < N_BUCKETS) {
        int incl = scanws[threadIdx.x];
        int st = incl - lsize[threadIdx.x];
        lstart[threadIdx.x] = st;
        lcur[threadIdx.x] = st;
        int c = lsize[threadIdx.x];
        gbase[threadIdx.x] = c ? (threadIdx.x * BCAP + atomicAdd(&bcnt[threadIdx.x], c)) : 0;
    }
    if (threadIdx.x == 0) lstart[N_BUCKETS] = cntE;
    __syncthreads();
    // 3) scatter into bucket-sorted LDS, recording bucket id per slot
    for (int i = s4 + (int)threadIdx.x; i < e4; i += (int)blockDim.x) {
        int4 r = row4[i];
        int4 c = col4[i];
        int pos, bk;
        bk = r.x >> 8; pos = atomicAdd(&lcur[bk], 1);
        staged[pos] = ((unsigned)(r.x & 255) << 18) | (unsigned)c.x; bktid[pos] = (unsigned short)bk;
        bk = r.y >> 8; pos = atomicAdd(&lcur[bk], 1);
        staged[pos] = ((unsigned)(r.y & 255) << 18) | (unsigned)c.y; bktid[pos] = (unsigned short)bk;
        bk = r.z >> 8; pos = atomicAdd(&lcur[bk], 1);
        staged[pos] = ((unsigned)(r.z & 255) << 18) | (unsigned)c.z; bktid[pos] = (unsigned short)bk;
        bk = r.w >> 8; pos = atomicAdd(&lcur[bk], 1);
        staged[pos] = ((unsigned)(r.w & 255) << 18) | (unsigned)c.w; bktid[pos] = (unsigned short)bk;
    }
    __syncthreads();
    // 4) sequential writeback: no search -- independent LDS reads
    for (int i = (int)threadIdx.x; i < cntE; i += (int)blockDim.x) {
        int bk = (int)bktid[i];
        ps[gbase[bk] + (i - lstart[bk])] = staged[i];
    }
}

// Pass 2: one block (512 thr) per bucket. Stage bucket edges in LDS, build
// 256-row hist, even-padded row starts, be, row-sort into LDS lsort,
// SEQUENTIAL coalesced ps writeback, and y0 = x0*rsqrt(deg) rows.
__global__ void fine_kernel(const int* __restrict__ bcnt, int* __restrict__ ps,
                            int2* __restrict__ be,
                            const float4* __restrict__ user, const float4* __restrict__ item,
                            uint2* __restrict__ yA) {
    __shared__ int ledge[BCAP];
    __shared__ int lsort[BCAP];
    __shared__ int rh[256];
    __shared__ int rsc[256];
    __shared__ int rcur[256];
    __shared__ float rq[256];
    int b = blockIdx.x;
    int base = b * BCAP;
    int cnt  = bcnt[b];
    if (cnt > BCAP) cnt = BCAP;          // defensive (never expected)
    if (threadIdx.x < 256) rh[threadIdx.x] = 0;
    __syncthreads();
    for (int i = threadIdx.x; i < cnt; i += blockDim.x) {
        int p = ps[base + i];
        ledge[i] = p;
        atomicAdd(&rh[p >> 18], 1);
    }
    __syncthreads();
    if (threadIdx.x < 256) rsc[threadIdx.x] = (rh[threadIdx.x] + 1) & ~1;  // even row size
    __syncthreads();
    for (int off = 1; off < 256; off <<= 1) {
        int t = (threadIdx.x < 256 && threadIdx.x >= off) ? rsc[threadIdx.x - off] : 0;
        __syncthreads();
        if (threadIdx.x < 256) rsc[threadIdx.x] += t;
        __syncthreads();
    }
    if (threadIdx.x < 256) {
        int r = threadIdx.x;
        int sz = (rh[r] + 1) & ~1;
        int pstart = rsc[r] - sz;            // even (base even, sizes even)
        rcur[r] = pstart;
        int n = (b << 8) + r;
        if (n < N_NODES) {
            int2 p; p.x = base + pstart; p.y = base + pstart + rh[r];
            be[n] = p;
            float d = (float)(rh[r] < 1 ? 1 : rh[r]);
            rq[r] = rsqrtf(d);
        }
    }
    __syncthreads();
    // row-sort scatter into LDS (int LDS atomics + LDS writes only)
    for (int i = threadIdx.x; i < cnt; i += blockDim.x) {
        int p = ledge[i];
        int pos = atomicAdd(&rcur[p >> 18], 1);      // LDS atomic
        lsort[pos] = p & 0x3FFFF;                    // sorted col, row bits stripped
    }
    __syncthreads();
    // sequential coalesced writeback of the padded layout (pads = garbage,
    // discarded by pull predicates before address formation)
    int tot = rsc[255];                              // padded total
    if (tot > BCAP) tot = BCAP;                      // defensive
    for (int i = threadIdx.x; i < tot; i += blockDim.x)
        ps[base + i] = lsort[i];
    // y0 rows for this bucket: 256 rows x 16 uint2 words; word w covers float4 w.
    for (int idx = threadIdx.x; idx < 4096; idx += blockDim.x) {
        int r = idx >> 4, w = idx & 15;
        int n = (b << 8) + r;
        if (n < N_NODES) {
            const float4* src = (n < NUM_USERS) ? (user + (size_t)n * 16)
                                                : (item + (size_t)(n - NUM_USERS) * 16);
            float4 v = src[w];
            float rn = rq[r];
            uint2 o;
            o.x = f2bf(v.x * rn) | (f2bf(v.y * rn) << 16);
            o.y = f2bf(v.z * rn) | (f2bf(v.w * rn) << 16);
            yA[(size_t)n * 16 + w] = o;
        }
    }
}

// 8 lanes per node, 8 nodes per wave (identity order: consecutive nodes ->
// contiguous scol runs + contiguous stores; R21/R25 lesson: ANY reorder
// loses). Lane q owns dims [8q,8q+8); 8-edge unroll: 4 int2 scol + 8 uint4
// gathers in flight. OOB -> dummy zero row N_NODES, predicated BEFORE
// addressing. Over-read <=24B past ps end lands in the slack before XA.
__device__ __forceinline__ void pull_sum(int2 bnd, int q,
                                         const int2* __restrict__ scol2,
                                         const uint4* __restrict__ xin, float2 sum[4]) {
    int endj = bnd.y;
    for (int j = bnd.x; j < endj; j += 8) {
        int h = j >> 1;
        int2 cc0 = scol2[h];
        int2 cc1 = scol2[h + 1];
        int2 cc2 = scol2[h + 2];
        int2 cc3 = scol2[h + 3];
        int c0 = cc0.x;                               // j < endj by loop cond
        int c1 = (j + 1 < endj) ? cc0.y : N_NODES;
        int c2 = (j + 2 < endj) ? cc1.x : N_NODES;
        int c3 = (j + 3 < endj) ? cc1.y : N_NODES;
        int c4 = (j + 4 < endj) ? cc2.x : N_NODES;
        int c5 = (j + 5 < endj) ? cc2.y : N_NODES;
        int c6 = (j + 6 < endj) ? cc3.x : N_NODES;
        int c7 = (j + 7 < endj) ? cc3.y : N_NODES;
        uint4 X0 = xin[(size_t)c0 * 8 + q];
        uint4 X1 = xin[(size_t)c1 * 8 + q];
        uint4 X2 = xin[(size_t)c2 * 8 + q];
        uint4 X3 = xin[(size_t)c3 * 8 + q];
        uint4 X4 = xin[(size_t)c4 * 8 + q];
        uint4 X5 = xin[(size_t)c5 * 8 + q];
        uint4 X6 = xin[(size_t)c6 * 8 + q];
        uint4 X7 = xin[(size_t)c7 * 8 + q];
        sum[0] += (bf2(X0.x) + bf2(X1.x)) + (bf2(X2.x) + bf2(X3.x))
                + (bf2(X4.x) + bf2(X5.x)) + (bf2(X6.x) + bf2(X7.x));
        sum[1] += (bf2(X0.y) + bf2(X1.y)) + (bf2(X2.y) + bf2(X3.y))
                + (bf2(X4.y) + bf2(X5.y)) + (bf2(X6.y) + bf2(X7.y));
        sum[2] += (bf2(X0.z) + bf2(X1.z)) + (bf2(X2.z) + bf2(X3.z))
                + (bf2(X4.z) + bf2(X5.z)) + (bf2(X6.z) + bf2(X7.z));
        sum[3] += (bf2(X0.w) + bf2(X1.w)) + (bf2(X2.w) + bf2(X3.w))
                + (bf2(X4.w) + bf2(X5.w)) + (bf2(X6.w) + bf2(X7.w));
    }
}

// Middle layers: y_{l+1}[n] = rsqrt(deg)^2 * sum  (bf16). All 64 lanes store.
__global__ void pull_kernel(const int2* __restrict__ be,
                            const int2* __restrict__ scol2,
                            const uint4* __restrict__ xin, uint4* __restrict__ xout) {
    int t = blockIdx.x * blockDim.x + (int)threadIdx.x;
    int n = t >> 3;
    if (n >= N_NODES) return;
    int q = t & 7;
    int2 bnd = be[n];
    float2 sum[4];
    sum[0] = make_float2(0.f, 0.f); sum[1] = make_float2(0.f, 0.f);
    sum[2] = make_float2(0.f, 0.f); sum[3] = make_float2(0.f, 0.f);
    pull_sum(bnd, q, scol2, xin, sum);
    int deg = bnd.y - bnd.x;
    float d = (float)(deg < 1 ? 1 : deg);
    float rn = rsqrtf(d);
    float s2 = rn * rn;
    uint4 p;
    p.x = f2bf(sum[0].x * s2) | (f2bf(sum[0].y * s2) << 16);
    p.y = f2bf(sum[1].x * s2) | (f2bf(sum[1].y * s2) << 16);
    p.z = f2bf(sum[2].x * s2) | (f2bf(sum[2].y * s2) << 16);
    p.w = f2bf(sum[3].x * s2) | (f2bf(sum[3].y * s2) << 16);
    xout[(size_t)n * 8 + q] = p;
}

// Last layer: acc = (x0 + (y1+y2)*sd + rn*sum) / 4, rn = rsqrt(deg), sd = sqrt(deg).
__global__ void pull_last_kernel(const int2* __restrict__ be,
                                 const int2* __restrict__ scol2,
                                 const uint4* __restrict__ xin,   // y2 (gather table)
                                 const uint4* __restrict__ xprev, // y1
                                 const float4* __restrict__ user, const float4* __restrict__ item,
                                 float4* __restrict__ acc4) {
    int t = blockIdx.x * blockDim.x + (int)threadIdx.x;
    int n = t >> 3;
    if (n >= N_NODES) return;
    int q = t & 7;
    int2 bnd = be[n];
    float2 sum[4];
    sum[0] = make_float2(0.f, 0.f); sum[1] = make_float2(0.f, 0.f);
    sum[2] = make_float2(0.f, 0.f); sum[3] = make_float2(0.f, 0.f);
    pull_sum(bnd, q, scol2, xin, sum);
    int deg = bnd.y - bnd.x;
    float d = (float)(deg < 1 ? 1 : deg);
    float rn = rsqrtf(d);
    float sd = sqrtf(d);
    uint4 p2 = xin  [(size_t)n * 8 + q];
    uint4 p1 = xprev[(size_t)n * 8 + q];
    const float4* x0 = (n < NUM_USERS) ? (user + (size_t)n * 16)
                                       : (item + (size_t)(n - NUM_USERS) * 16);
    float4 a0 = x0[q * 2], a1 = x0[q * 2 + 1];
    float4 o0, o1;
    o0.x = (a0.x + (bflo(p1.x) + bflo(p2.x)) * sd + rn * sum[0].x) * 0.25f;
    o0.y = (a0.y + (bfhi(p1.x) + bfhi(p2.x)) * sd + rn * sum[0].y) * 0.25f;
    o0.z = (a0.z + (bflo(p1.y) + bflo(p2.y)) * sd + rn * sum[1].x) * 0.25f;
    o0.w = (a0.w + (bfhi(p1.y) + bfhi(p2.y)) * sd + rn * sum[1].y) * 0.25f;
    o1.x = (a1.x + (bflo(p1.z) + bflo(p2.z)) * sd + rn * sum[2].x) * 0.25f;
    o1.y = (a1.y + (bfhi(p1.z) + bfhi(p2.z)) * sd + rn * sum[2].y) * 0.25f;
    o1.z = (a1.z + (bflo(p1.w) + bflo(p2.w)) * sd + rn * sum[3].x) * 0.25f;
    o1.w = (a1.w + (bfhi(p1.w) + bfhi(p2.w)) * sd + rn * sum[3].y) * 0.25f;
    size_t o4 = (size_t)n * 16 + q * 2;
    acc4[o4] = o0;
    acc4[o4 + 1] = o1;
}

extern "C" void kernel_launch(void* const* d_in, const int* in_sizes, int n_in,
                              void* d_out, int out_size, void* d_ws, size_t ws_size,
                              hipStream_t stream) {
    const float* user = (const float*)d_in[0];
    const float* item = (const float*)d_in[1];
    const int*   ei   = (const int*)d_in[2];
    const int* row = ei;            // edge_index[0]
    const int* col = ei + N_EDGES;  // edge_index[1]

    char*  ws   = (char*)d_ws;
    int*   bcnt = (int*)(ws + OFF_BCNT);
    int2*  be   = (int2*)(ws + OFF_BE);
    int*   ps   = (int*)(ws + OFF_PS);
    char*  xA   = ws + OFF_XA;   // bf16 y-tables, (N+1) rows (row N = zeros)
    char*  xB   = ws + OFF_XB;
    float* acc  = (float*)d_out;

    // CSR build: LDS-staged partition (bktid writeback) -> fine (LDS sort)
    hipMemsetAsync(bcnt, 0, 4096, stream);
    partition_kernel<<<PART_BLOCKS, 1024, 0, stream>>>((const int4*)row, (const int4*)col,
                                                       bcnt, (unsigned*)ps,
                                                       (uint2*)xA, (uint2*)xB);
    fine_kernel<<<N_BUCKETS, 512, 0, stream>>>(bcnt, ps, be,
                                               (const float4*)user, (const float4*)item,
                                               (uint2*)xA);

    // 3 pull layers: 8 threads per node, identity node order
    const int grid = (N_NODES * 8 + 255) / 256;
    pull_kernel<<<grid, 256, 0, stream>>>(be, (const int2*)ps,
        (const uint4*)xA, (uint4*)xB);
    pull_kernel<<<grid, 256, 0, stream>>>(be, (const int2*)ps,
        (const uint4*)xB, (uint4*)xA);
    pull_last_kernel<<<grid, 256, 0, stream>>>(be, (const int2*)ps,
        (const uint4*)xA, (const uint4*)xB,
        (const float4*)user, (const float4*)item, (float4*)acc);
}